// Round 14
// baseline (26.357 us; speedup 1.0000x reference)
//
#include <hip/hip_runtime.h>

#define BB 4
#define SS 4096
#define EE 128

typedef __attribute__((ext_vector_type(8))) short bf16x8;
typedef __attribute__((ext_vector_type(4))) float f32x4;

__device__ __forceinline__ unsigned short f2bf(float f) {
    unsigned u = __float_as_uint(f);
    u = (u + 0x7FFFu + ((u >> 16) & 1u)) >> 16;
    return (unsigned short)u;
}
__device__ __forceinline__ float bf2f(unsigned short h) {
    return __uint_as_float(((unsigned)h) << 16);
}
// round-to-nearest split (A-operands)
__device__ __forceinline__ void split8(const float* p, bf16x8& h, bf16x8& l) {
    float4 v0 = *reinterpret_cast<const float4*>(p);
    float4 v1 = *reinterpret_cast<const float4*>(p + 4);
    float f[8] = {v0.x, v0.y, v0.z, v0.w, v1.x, v1.y, v1.z, v1.w};
    #pragma unroll
    for (int i = 0; i < 8; ++i) {
        unsigned short hb = f2bf(f[i]);
        h[i] = (short)hb;
        l[i] = (short)f2bf(f[i] - bf2f(hb));
    }
}
// cheap truncating split (B-operands)
__device__ __forceinline__ void split8t(const float* p, bf16x8& h, bf16x8& l) {
    float4 v0 = *reinterpret_cast<const float4*>(p);
    float4 v1 = *reinterpret_cast<const float4*>(p + 4);
    float f[8] = {v0.x, v0.y, v0.z, v0.w, v1.x, v1.y, v1.z, v1.w};
    #pragma unroll
    for (int i = 0; i < 8; ++i) {
        unsigned hb = __float_as_uint(f[i]) >> 16;
        h[i] = (short)hb;
        float lo = f[i] - __uint_as_float(hb << 16);
        l[i] = (short)(__float_as_uint(lo) >> 16);
    }
}
// 3-product split-bf16 MFMA: ~f32 accuracy (drops lo*lo)
__device__ __forceinline__ f32x4 mfma3(bf16x8 ah, bf16x8 al, bf16x8 bh, bf16x8 bl, f32x4 c) {
    c = __builtin_amdgcn_mfma_f32_16x16x32_bf16(ah, bh, c, 0, 0, 0);
    c = __builtin_amdgcn_mfma_f32_16x16x32_bf16(al, bh, c, 0, 0, 0);
    c = __builtin_amdgcn_mfma_f32_16x16x32_bf16(ah, bl, c, 0, 0, 0);
    return c;
}

// ---------------------------------------------------------------------------
// prep: blocks [0,256): b=bx>>6, i=bx&63: chunk colsum of x[b, 64+63i..+63, :]
//         projected through Wv: vpart[b][i][c] = xsum_i . Wv[c]  (f32)
//       blocks [256,268): idx=bx-256, b=idx/3, role=idx%3, MFMA GEMMs with
//         row-major LDS staging (r12 discipline):
//         role 0/1: Vt[b][v][t] = bf16( x64 @ Wv^T )  (transposed store)
//         role 2:   K-GEMM -> masked ksub (LDS) -> stage wqT -> Mt-GEMM ->
//                   Mth/Mtl[t][e] bf16 hi/lo.  (prep2 is gone)
// ---------------------------------------------------------------------------
__global__ __launch_bounds__(256, 2)
void prep(const float* __restrict__ x, const float* __restrict__ Wk,
          const float* __restrict__ Wq, const float* __restrict__ Wv,
          unsigned short* __restrict__ Vt,
          unsigned short* __restrict__ Mth, unsigned short* __restrict__ Mtl,
          float* __restrict__ vpart)
{
    __shared__ float xs[64][132];   // 33792 B
    __shared__ float ws[64][132];   // 33792 B
    const int tid = threadIdx.x;
    const int bx = blockIdx.x;

    if (bx < 256) {
        // ---- vpart producer: chunk colsum + Wv projection ----
        float* xred = &ws[0][0];     // [0:128) rg0, [128:256) rg1, [256:384) xsum
        const int b = bx >> 6, i = bx & 63;
        const size_t base = ((size_t)b * SS + 64 + (size_t)i * 63) * EE;
        const int col = tid & 127, rg = tid >> 7;
        float s = 0.f;
        for (int r = rg; r < 63; r += 2)
            s += x[base + (size_t)r * EE + col];
        xred[rg * 128 + col] = s;
        __syncthreads();
        if (tid < 128) xred[256 + tid] = xred[tid] + xred[128 + tid];
        __syncthreads();
        if (tid < 128) {
            float a = 0.f;
            #pragma unroll 8
            for (int e = 0; e < 128; e += 4) {
                float4 wv = *reinterpret_cast<const float4*>(Wv + (size_t)tid * EE + e);
                a = fmaf(xred[256 + e + 0], wv.x, a);
                a = fmaf(xred[256 + e + 1], wv.y, a);
                a = fmaf(xred[256 + e + 2], wv.z, a);
                a = fmaf(xred[256 + e + 3], wv.w, a);
            }
            vpart[((size_t)b * 64 + i) * 128 + tid] = a;
        }
        return;
    }

    // ================== special blocks ==================
    const int idx = bx - 256;
    const int b = idx / 3, role = idx % 3;
    const float* Wbase = (role == 0) ? Wv : (role == 1) ? (Wv + 64 * EE) : Wk;

    #pragma unroll
    for (int i = 0; i < 8; ++i) {               // stage x64, row-major
        int f4 = tid + i * 256;
        int row = f4 >> 5, kq = f4 & 31;
        *reinterpret_cast<float4*>(&xs[row][4 * kq]) =
            *reinterpret_cast<const float4*>(x + ((size_t)b * SS + row) * EE + 4 * kq);
    }
    #pragma unroll
    for (int i = 0; i < 8; ++i) {               // stage W rows, row-major
        int f4 = tid + i * 256;
        int row = f4 >> 5, kq = f4 & 31;
        *reinterpret_cast<float4*>(&ws[row][4 * kq]) =
            *reinterpret_cast<const float4*>(Wbase + (size_t)row * EE + 4 * kq);
    }
    __syncthreads();

    const int l = tid & 63, w = tid >> 6;
    const int lm = l & 15, lg = l >> 4;
    const int t0 = w * 16;

    bf16x8 xh[4], xl[4];
    #pragma unroll
    for (int kt = 0; kt < 4; ++kt)
        split8(&xs[t0 + lm][kt * 32 + lg * 8], xh[kt], xl[kt]);

    float kacc[4][4];                            // role-2: masked K values
    #pragma unroll
    for (int ct = 0; ct < 4; ++ct) {
        f32x4 a = {0.f, 0.f, 0.f, 0.f};
        #pragma unroll
        for (int kt = 0; kt < 4; ++kt) {
            bf16x8 bh, bl;
            split8t(&ws[ct * 16 + lm][kt * 32 + lg * 8], bh, bl);
            a = mfma3(xh[kt], xl[kt], bh, bl, a);
        }
        const int col = ct * 16 + lm;
        if (role <= 1) {
            const int voff = role * 64;
            ushort4 pk = make_ushort4(f2bf(a[0]), f2bf(a[1]), f2bf(a[2]), f2bf(a[3]));
            *reinterpret_cast<ushort4*>(Vt + (size_t)b * 8192 +
                                        (size_t)(voff + col) * 64 + t0 + lg * 4) = pk;
        } else {
            const int tb = t0 + lg * 4;
            kacc[ct][0] = (tb + 0 <= col) ? a[0] : 0.f;
            kacc[ct][1] = (tb + 1 <= col) ? a[1] : 0.f;
            kacc[ct][2] = (tb + 2 <= col) ? a[2] : 0.f;
            kacc[ct][3] = (tb + 3 <= col) ? a[3] : 0.f;
        }
    }
    if (role <= 1) return;

    // ---- role 2 continues: ksub -> LDS (ws region), wqT -> LDS (xs region) ----
    __syncthreads();                             // all reads of xs/ws done
    float (*ksub)[68] = reinterpret_cast<float (*)[68]>(&ws[0][0]);   // [t][j]
    float (*wqT)[66]  = reinterpret_cast<float (*)[66]>(&xs[0][0]);   // [e][j]
    #pragma unroll
    for (int ct = 0; ct < 4; ++ct) {
        const int j = ct * 16 + lm, tb = t0 + lg * 4;
        #pragma unroll
        for (int r = 0; r < 4; ++r)
            ksub[tb + r][j] = kacc[ct][r];
    }
    #pragma unroll
    for (int i = 0; i < 8; ++i) {               // stage Wq transposed: wqT[e][j]
        int f4 = tid + i * 256;
        int j = f4 >> 5, eq = f4 & 31;
        float4 v = *reinterpret_cast<const float4*>(Wq + (size_t)j * EE + 4 * eq);
        wqT[4 * eq + 0][j] = v.x;
        wqT[4 * eq + 1][j] = v.y;
        wqT[4 * eq + 2][j] = v.z;
        wqT[4 * eq + 3][j] = v.w;
    }
    __syncthreads();

    // ---- Mt-GEMM: Mt[t][e] = sum_j ksub[t][j] * Wq[j][e] ----
    bf16x8 kh[2], kl[2];
    #pragma unroll
    for (int kt2 = 0; kt2 < 2; ++kt2)
        split8(&ksub[t0 + lm][kt2 * 32 + lg * 8], kh[kt2], kl[kt2]);
    #pragma unroll
    for (int et = 0; et < 8; ++et) {
        f32x4 a = {0.f, 0.f, 0.f, 0.f};
        #pragma unroll
        for (int kt2 = 0; kt2 < 2; ++kt2) {
            bf16x8 qh, ql;
            split8t(&wqT[et * 16 + lm][kt2 * 32 + lg * 8], qh, ql);
            a = mfma3(kh[kt2], kl[kt2], qh, ql, a);
        }
        const int e = et * 16 + lm, tb = t0 + lg * 4;
        #pragma unroll
        for (int r = 0; r < 4; ++r) {
            const size_t off = (size_t)b * 8192 + (size_t)(tb + r) * 128 + e;
            unsigned short hb = f2bf(a[r]);
            Mth[off] = hb;
            Mtl[off] = f2bf(a[r] - bf2f(hb));
        }
    }
}

// ---------------------------------------------------------------------------
// attn_main: 256 blocks x 4 waves (64 rows/block). Prologue reduces 64
// fixed-order vpart partials -> vsS. Then per wave: S = x@Mt split-MFMA,
// softmax (+4032 zero cols), P relayout via LDS, PV MFMA + vsum term + store.
// ---------------------------------------------------------------------------
__global__ __launch_bounds__(256, 2)
void attn_main(const float* __restrict__ x, const short* __restrict__ Mth,
               const short* __restrict__ Mtl, const short* __restrict__ Vt,
               const float* __restrict__ vpart, float* __restrict__ out)
{
    __shared__ float Plds[64][68];
    __shared__ float vsred[2][128];
    __shared__ float vsS[128];
    const int tid = threadIdx.x;
    const int bx = blockIdx.x;
    const int b = bx >> 6;
    const int s0 = (bx & 63) * 64;
    const int l = tid & 63, w = tid >> 6;
    const int lm = l & 15, lg = l >> 4;
    const int srow = s0 + w * 16;

    // x A-frags first (global loads issue early)
    bf16x8 xh[4], xl[4];
    const float* xrow = x + ((size_t)b * SS + srow + lm) * EE + lg * 8;
    #pragma unroll
    for (int kt = 0; kt < 4; ++kt)
        split8(xrow + kt * 32, xh[kt], xl[kt]);

    // vsum: reduce 64 vpart partials, fixed order (deterministic)
    {
        const int col = tid & 127, half = tid >> 7;
        float s = 0.f;
        #pragma unroll 8
        for (int i = half * 32; i < half * 32 + 32; ++i)
            s += vpart[(size_t)b * 8192 + (size_t)i * 128 + col];
        vsred[half][col] = s;
    }
    __syncthreads();
    if (tid < 128) vsS[tid] = vsred[0][tid] + vsred[1][tid];
    __syncthreads();

    // S = x @ Mt : 4 col-tiles x (4 k-tiles x 3 split-mfma)
    f32x4 sa[4];
    const short* mh_base = Mth + (size_t)b * 8192 + lg * 8;
    const short* ml_base = Mtl + (size_t)b * 8192 + lg * 8;
    #pragma unroll
    for (int ct = 0; ct < 4; ++ct) {
        f32x4 a = {0.f, 0.f, 0.f, 0.f};
        const size_t trow = (size_t)(ct * 16 + lm) * 128;
        #pragma unroll
        for (int kt = 0; kt < 4; ++kt) {
            bf16x8 mh = *reinterpret_cast<const bf16x8*>(mh_base + trow + kt * 32);
            bf16x8 ml = *reinterpret_cast<const bf16x8*>(ml_base + trow + kt * 32);
            a = __builtin_amdgcn_mfma_f32_16x16x32_bf16(xh[kt], mh, a, 0, 0, 0);
            a = __builtin_amdgcn_mfma_f32_16x16x32_bf16(xl[kt], mh, a, 0, 0, 0);
            a = __builtin_amdgcn_mfma_f32_16x16x32_bf16(xh[kt], ml, a, 0, 0, 0);
        }
        sa[ct] = a;
    }

    // softmax over 4096 cols (64 real + 4032 exact zeros)
    float e[4], iz[4];
    #pragma unroll
    for (int r = 0; r < 4; ++r) {
        float m = fmaxf(fmaxf(sa[0][r], sa[1][r]), fmaxf(sa[2][r], sa[3][r]));
        #pragma unroll
        for (int o = 1; o < 16; o <<= 1) m = fmaxf(m, __shfl_xor(m, o));
        m = fmaxf(m, 0.f);
        float w0 = __expf(sa[0][r] - m), w1 = __expf(sa[1][r] - m);
        float w2 = __expf(sa[2][r] - m), w3 = __expf(sa[3][r] - m);
        sa[0][r] = w0; sa[1][r] = w1; sa[2][r] = w2; sa[3][r] = w3;
        float z = (w0 + w1) + (w2 + w3);
        #pragma unroll
        for (int o = 1; o < 16; o <<= 1) z += __shfl_xor(z, o);
        e[r] = __expf(-m);
        z += 4032.f * e[r];
        iz[r] = 1.f / z;
    }

    // P relayout (per-wave rows, same-wave write->read; no barrier needed)
    #pragma unroll
    for (int ct = 0; ct < 4; ++ct)
        #pragma unroll
        for (int r = 0; r < 4; ++r)
            Plds[w * 16 + lg * 4 + r][ct * 16 + lm] = sa[ct][r];
    bf16x8 pf[2];
    #pragma unroll
    for (int kt2 = 0; kt2 < 2; ++kt2) {
        const float* pr = &Plds[w * 16 + lm][kt2 * 32 + lg * 8];
        #pragma unroll
        for (int i = 0; i < 8; ++i) pf[kt2][i] = (short)f2bf(pr[i]);
    }

    // PV + vsum term + normalize + store
    const short* vb = Vt + (size_t)b * 8192 + lg * 8;
    const size_t obase = ((size_t)b * SS + srow) * EE;
    #pragma unroll
    for (int ct = 0; ct < 8; ++ct) {
        const int col = ct * 16 + lm;
        bf16x8 v0 = *reinterpret_cast<const bf16x8*>(vb + (size_t)col * 64);
        bf16x8 v1 = *reinterpret_cast<const bf16x8*>(vb + (size_t)col * 64 + 32);
        f32x4 a = {0.f, 0.f, 0.f, 0.f};
        a = __builtin_amdgcn_mfma_f32_16x16x32_bf16(pf[0], v0, a, 0, 0, 0);
        a = __builtin_amdgcn_mfma_f32_16x16x32_bf16(pf[1], v1, a, 0, 0, 0);
        const float vs = vsS[col];
        #pragma unroll
        for (int r = 0; r < 4; ++r)
            out[obase + (size_t)(lg * 4 + r) * EE + col] = (a[r] + e[r] * vs) * iz[r];
    }
}

// ---------------------------------------------------------------------------
extern "C" void kernel_launch(void* const* d_in, const int* in_sizes, int n_in,
                              void* d_out, int out_size, void* d_ws, size_t ws_size,
                              hipStream_t stream)
{
    const float* x  = (const float*)d_in[0];
    const float* Wk = (const float*)d_in[1];
    const float* Wq = (const float*)d_in[2];
    const float* Wv = (const float*)d_in[3];
    float* out = (float*)d_out;

    float* vpart = (float*)d_ws;                            // 4*64*128 f32
    unsigned short* Mth = (unsigned short*)(vpart + 32768); // 4*64*128 bf16
    unsigned short* Mtl = Mth + 32768;                      // 4*64*128 bf16
    unsigned short* Vt  = Mtl + 32768;                      // 4*128*64 bf16

    prep<<<268, 256, 0, stream>>>(x, Wk, Wq, Wv, Vt, Mth, Mtl, vpart);
    attn_main<<<256, 256, 0, stream>>>(
        x, (const short*)Mth, (const short*)Mtl, (const short*)Vt, vpart, out);
}

// Round 15
// 25.934 us; speedup vs baseline: 1.0163x; 1.0163x over previous
//
#include <hip/hip_runtime.h>

#define BB 4
#define SS 4096
#define EE 128

typedef __attribute__((ext_vector_type(8))) short bf16x8;
typedef __attribute__((ext_vector_type(4))) float f32x4;

__device__ __forceinline__ unsigned short f2bf(float f) {
    unsigned u = __float_as_uint(f);
    u = (u + 0x7FFFu + ((u >> 16) & 1u)) >> 16;
    return (unsigned short)u;
}
__device__ __forceinline__ float bf2f(unsigned short h) {
    return __uint_as_float(((unsigned)h) << 16);
}
// round-to-nearest split
__device__ __forceinline__ void split8(const float* p, bf16x8& h, bf16x8& l) {
    float4 v0 = *reinterpret_cast<const float4*>(p);
    float4 v1 = *reinterpret_cast<const float4*>(p + 4);
    float f[8] = {v0.x, v0.y, v0.z, v0.w, v1.x, v1.y, v1.z, v1.w};
    #pragma unroll
    for (int i = 0; i < 8; ++i) {
        unsigned short hb = f2bf(f[i]);
        h[i] = (short)hb;
        l[i] = (short)f2bf(f[i] - bf2f(hb));
    }
}
// cheap truncating split (prep1 B-operand)
__device__ __forceinline__ void split8t(const float* p, bf16x8& h, bf16x8& l) {
    float4 v0 = *reinterpret_cast<const float4*>(p);
    float4 v1 = *reinterpret_cast<const float4*>(p + 4);
    float f[8] = {v0.x, v0.y, v0.z, v0.w, v1.x, v1.y, v1.z, v1.w};
    #pragma unroll
    for (int i = 0; i < 8; ++i) {
        unsigned hb = __float_as_uint(f[i]) >> 16;
        h[i] = (short)hb;
        float lo = f[i] - __uint_as_float(hb << 16);
        l[i] = (short)(__float_as_uint(lo) >> 16);
    }
}
// 3-product split-bf16 MFMA: ~f32 accuracy (drops lo*lo)
__device__ __forceinline__ f32x4 mfma3(bf16x8 ah, bf16x8 al, bf16x8 bh, bf16x8 bl, f32x4 c) {
    c = __builtin_amdgcn_mfma_f32_16x16x32_bf16(ah, bh, c, 0, 0, 0);
    c = __builtin_amdgcn_mfma_f32_16x16x32_bf16(al, bh, c, 0, 0, 0);
    c = __builtin_amdgcn_mfma_f32_16x16x32_bf16(ah, bl, c, 0, 0, 0);
    return c;
}

// ---------------------------------------------------------------------------
// prep1: blocks [0,256): xpart chunk column-sums;
//   blocks [256,268): MFMA 64x64 GEMMs (row-major LDS staging):
//     role 0/1: Vt[b][v][t] = bf16( x64 @ Wv^T );  role 2: masked key64T f32.
// ---------------------------------------------------------------------------
__global__ __launch_bounds__(256, 2)
void prep1(const float* __restrict__ x, const float* __restrict__ Wk,
           const float* __restrict__ Wv,
           unsigned short* __restrict__ Vt, float* __restrict__ key64T,
           float* __restrict__ xpart)
{
    __shared__ float xs[64][132];
    __shared__ float ws[64][132];
    const int tid = threadIdx.x;
    const int bx = blockIdx.x;

    if (bx < 256) {
        __shared__ float xred[2][128];
        const int b = bx >> 6, i = bx & 63;
        const size_t base = ((size_t)b * SS + 64 + (size_t)i * 63) * EE;
        const int col = tid & 127, rg = tid >> 7;
        float s = 0.f;
        for (int r = rg; r < 63; r += 2)
            s += x[base + (size_t)r * EE + col];
        xred[rg][col] = s;
        __syncthreads();
        if (tid < 128)
            xpart[((size_t)b * 64 + i) * 128 + tid] = xred[0][tid] + xred[1][tid];
        return;
    }

    const int idx = bx - 256;
    const int b = idx / 3, role = idx % 3;
    const float* Wbase = (role == 0) ? Wv : (role == 1) ? (Wv + 64 * EE) : Wk;

    #pragma unroll
    for (int i = 0; i < 8; ++i) {
        int f4 = tid + i * 256;
        int row = f4 >> 5, kq = f4 & 31;
        *reinterpret_cast<float4*>(&xs[row][4 * kq]) =
            *reinterpret_cast<const float4*>(x + ((size_t)b * SS + row) * EE + 4 * kq);
    }
    #pragma unroll
    for (int i = 0; i < 8; ++i) {
        int f4 = tid + i * 256;
        int row = f4 >> 5, kq = f4 & 31;
        *reinterpret_cast<float4*>(&ws[row][4 * kq]) =
            *reinterpret_cast<const float4*>(Wbase + (size_t)row * EE + 4 * kq);
    }
    __syncthreads();

    const int l = tid & 63, w = tid >> 6;
    const int lm = l & 15, lg = l >> 4;
    const int t0 = w * 16;

    bf16x8 xh[4], xl[4];
    #pragma unroll
    for (int kt = 0; kt < 4; ++kt)
        split8(&xs[t0 + lm][kt * 32 + lg * 8], xh[kt], xl[kt]);

    #pragma unroll
    for (int ct = 0; ct < 4; ++ct) {
        f32x4 a = {0.f, 0.f, 0.f, 0.f};
        #pragma unroll
        for (int kt = 0; kt < 4; ++kt) {
            bf16x8 bh, bl;
            split8t(&ws[ct * 16 + lm][kt * 32 + lg * 8], bh, bl);
            a = mfma3(xh[kt], xl[kt], bh, bl, a);
        }
        const int col = ct * 16 + lm;
        if (role <= 1) {
            const int voff = role * 64;
            ushort4 pk = make_ushort4(f2bf(a[0]), f2bf(a[1]), f2bf(a[2]), f2bf(a[3]));
            *reinterpret_cast<ushort4*>(Vt + (size_t)b * 8192 +
                                        (size_t)(voff + col) * 64 + t0 + lg * 4) = pk;
        } else {
            const int tb = t0 + lg * 4;
            float4 kv = make_float4((tb + 0 <= col) ? a[0] : 0.f,
                                    (tb + 1 <= col) ? a[1] : 0.f,
                                    (tb + 2 <= col) ? a[2] : 0.f,
                                    (tb + 3 <= col) ? a[3] : 0.f);
            *reinterpret_cast<float4*>(key64T + ((size_t)b * 64 + col) * 64 + tb) = kv;
        }
    }
}

// ---------------------------------------------------------------------------
// prep2: blocks [0,16): Mt bf16 hi/lo from key64T;
//        blocks [16,20): vsum[b] = (sum_i xpart[b][i]) @ Wv^T  (f32)
// ---------------------------------------------------------------------------
__global__ __launch_bounds__(256)
void prep2(const float* __restrict__ Wq, const float* __restrict__ Wv,
           const float* __restrict__ key64T, const float* __restrict__ xpart,
           unsigned short* __restrict__ Mth, unsigned short* __restrict__ Mtl,
           float* __restrict__ vsum)
{
    const int tid = threadIdx.x, bx = blockIdx.x;
    if (bx < 16) {
        __shared__ float ks[64][66];
        __shared__ float wqs[64][36];
        const int b = bx >> 2, kq = bx & 3;
        #pragma unroll
        for (int i = 0; i < 4; ++i) {
            int f4 = tid + i * 256;
            int j = f4 >> 4, t4 = f4 & 15;
            float4 v = *reinterpret_cast<const float4*>(key64T + (size_t)b * 4096 + (size_t)j * 64 + 4 * t4);
            *reinterpret_cast<float4*>(&ks[j][4 * t4]) = v;
        }
        #pragma unroll
        for (int i = 0; i < 2; ++i) {
            int f4 = tid + i * 256;
            int j = f4 >> 3, kk = f4 & 7;
            float4 v = *reinterpret_cast<const float4*>(Wq + (size_t)j * EE + kq * 32 + 4 * kk);
            *reinterpret_cast<float4*>(&wqs[j][4 * kk]) = v;
        }
        __syncthreads();
        const int t0 = (tid >> 3) * 2, k0 = (tid & 7) * 4;
        float acc[2][4] = {};
        #pragma unroll
        for (int j = 0; j < 64; ++j) {
            float4 w4 = *reinterpret_cast<const float4*>(&wqs[j][k0]);
            float kv0 = ks[j][t0], kv1 = ks[j][t0 + 1];
            acc[0][0] = fmaf(kv0, w4.x, acc[0][0]);
            acc[0][1] = fmaf(kv0, w4.y, acc[0][1]);
            acc[0][2] = fmaf(kv0, w4.z, acc[0][2]);
            acc[0][3] = fmaf(kv0, w4.w, acc[0][3]);
            acc[1][0] = fmaf(kv1, w4.x, acc[1][0]);
            acc[1][1] = fmaf(kv1, w4.y, acc[1][1]);
            acc[1][2] = fmaf(kv1, w4.z, acc[1][2]);
            acc[1][3] = fmaf(kv1, w4.w, acc[1][3]);
        }
        #pragma unroll
        for (int dt = 0; dt < 2; ++dt) {
            unsigned short h0 = f2bf(acc[dt][0]), h1 = f2bf(acc[dt][1]);
            unsigned short h2 = f2bf(acc[dt][2]), h3 = f2bf(acc[dt][3]);
            ushort4 hv = make_ushort4(h0, h1, h2, h3);
            ushort4 lv = make_ushort4(f2bf(acc[dt][0] - bf2f(h0)),
                                      f2bf(acc[dt][1] - bf2f(h1)),
                                      f2bf(acc[dt][2] - bf2f(h2)),
                                      f2bf(acc[dt][3] - bf2f(h3)));
            const size_t off = (size_t)b * 8192 + (size_t)(t0 + dt) * 128 + kq * 32 + k0;
            *reinterpret_cast<ushort4*>(Mth + off) = hv;
            *reinterpret_cast<ushort4*>(Mtl + off) = lv;
        }
    } else {
        __shared__ float xsum[128];
        const int b = bx - 16;
        if (tid < 128) {
            float s = 0.f;
            #pragma unroll 8
            for (int i = 0; i < 64; ++i) s += xpart[((size_t)b * 64 + i) * 128 + tid];
            xsum[tid] = s;
        }
        __syncthreads();
        if (tid < 128) {
            float a = 0.f;
            #pragma unroll 8
            for (int e = 0; e < 128; e += 4) {
                float4 w = *reinterpret_cast<const float4*>(Wv + (size_t)tid * EE + e);
                a = fmaf(xsum[e + 0], w.x, a);
                a = fmaf(xsum[e + 1], w.y, a);
                a = fmaf(xsum[e + 2], w.z, a);
                a = fmaf(xsum[e + 3], w.w, a);
            }
            vsum[(size_t)b * EE + tid] = a;
        }
    }
}

// ---------------------------------------------------------------------------
// attn_main: 256 blocks x 4 waves (64 rows/block) — amortizes Mth/Mtl/Vt
// L2 reads 4x vs the 1-wave shape. Per wave: 16 rows, S = x@Mt split-MFMA,
// softmax (+4032 zero cols), P relayout, PV + vsum term.
// ---------------------------------------------------------------------------
__global__ __launch_bounds__(256, 2)
void attn_main(const float* __restrict__ x, const short* __restrict__ Mth,
               const short* __restrict__ Mtl, const short* __restrict__ Vt,
               const float* __restrict__ vsum, float* __restrict__ out)
{
    __shared__ float Plds[64][68];
    __shared__ float vsS[128];
    const int tid = threadIdx.x;
    const int bx = blockIdx.x;
    const int b = bx >> 6;
    const int s0 = (bx & 63) * 64;
    const int l = tid & 63, w = tid >> 6;
    const int lm = l & 15, lg = l >> 4;
    const int srow = s0 + w * 16;

    if (tid < 128) vsS[tid] = vsum[(size_t)b * EE + tid];

    // x A-frags (hi/lo split)
    bf16x8 xh[4], xl[4];
    const float* xrow = x + ((size_t)b * SS + srow + lm) * EE + lg * 8;
    #pragma unroll
    for (int kt = 0; kt < 4; ++kt)
        split8(xrow + kt * 32, xh[kt], xl[kt]);

    // S = x @ Mt : 4 col-tiles x (4 k-tiles x 3 split-mfma)
    f32x4 sa[4];
    const short* mh_base = Mth + (size_t)b * 8192 + lg * 8;
    const short* ml_base = Mtl + (size_t)b * 8192 + lg * 8;
    #pragma unroll
    for (int ct = 0; ct < 4; ++ct) {
        f32x4 a = {0.f, 0.f, 0.f, 0.f};
        const size_t trow = (size_t)(ct * 16 + lm) * 128;
        #pragma unroll
        for (int kt = 0; kt < 4; ++kt) {
            bf16x8 mh = *reinterpret_cast<const bf16x8*>(mh_base + trow + kt * 32);
            bf16x8 ml = *reinterpret_cast<const bf16x8*>(ml_base + trow + kt * 32);
            a = __builtin_amdgcn_mfma_f32_16x16x32_bf16(xh[kt], mh, a, 0, 0, 0);
            a = __builtin_amdgcn_mfma_f32_16x16x32_bf16(xl[kt], mh, a, 0, 0, 0);
            a = __builtin_amdgcn_mfma_f32_16x16x32_bf16(xh[kt], ml, a, 0, 0, 0);
        }
        sa[ct] = a;
    }

    // softmax over 4096 cols (64 real + 4032 exact zeros)
    float e[4], iz[4];
    #pragma unroll
    for (int r = 0; r < 4; ++r) {
        float m = fmaxf(fmaxf(sa[0][r], sa[1][r]), fmaxf(sa[2][r], sa[3][r]));
        #pragma unroll
        for (int o = 1; o < 16; o <<= 1) m = fmaxf(m, __shfl_xor(m, o));
        m = fmaxf(m, 0.f);
        float w0 = __expf(sa[0][r] - m), w1 = __expf(sa[1][r] - m);
        float w2 = __expf(sa[2][r] - m), w3 = __expf(sa[3][r] - m);
        sa[0][r] = w0; sa[1][r] = w1; sa[2][r] = w2; sa[3][r] = w3;
        float z = (w0 + w1) + (w2 + w3);
        #pragma unroll
        for (int o = 1; o < 16; o <<= 1) z += __shfl_xor(z, o);
        e[r] = __expf(-m);
        z += 4032.f * e[r];
        iz[r] = 1.f / z;
    }

    // P relayout (per-wave rows): C/D layout -> A-frag layout via LDS
    __syncthreads();   // vsS visible; Plds regions are per-wave disjoint
    #pragma unroll
    for (int ct = 0; ct < 4; ++ct)
        #pragma unroll
        for (int r = 0; r < 4; ++r)
            Plds[w * 16 + lg * 4 + r][ct * 16 + lm] = sa[ct][r];
    bf16x8 pf[2];
    #pragma unroll
    for (int kt2 = 0; kt2 < 2; ++kt2) {
        const float* pr = &Plds[w * 16 + lm][kt2 * 32 + lg * 8];
        #pragma unroll
        for (int i = 0; i < 8; ++i) pf[kt2][i] = (short)f2bf(pr[i]);
    }

    // PV + vsum term + normalize + store
    const short* vb = Vt + (size_t)b * 8192 + lg * 8;
    const size_t obase = ((size_t)b * SS + srow) * EE;
    #pragma unroll
    for (int ct = 0; ct < 8; ++ct) {
        const int col = ct * 16 + lm;
        bf16x8 v0 = *reinterpret_cast<const bf16x8*>(vb + (size_t)col * 64);
        bf16x8 v1 = *reinterpret_cast<const bf16x8*>(vb + (size_t)col * 64 + 32);
        f32x4 a = {0.f, 0.f, 0.f, 0.f};
        a = __builtin_amdgcn_mfma_f32_16x16x32_bf16(pf[0], v0, a, 0, 0, 0);
        a = __builtin_amdgcn_mfma_f32_16x16x32_bf16(pf[1], v1, a, 0, 0, 0);
        const float vs = vsS[col];
        #pragma unroll
        for (int r = 0; r < 4; ++r)
            out[obase + (size_t)(lg * 4 + r) * EE + col] = (a[r] + e[r] * vs) * iz[r];
    }
}

// ---------------------------------------------------------------------------
extern "C" void kernel_launch(void* const* d_in, const int* in_sizes, int n_in,
                              void* d_out, int out_size, void* d_ws, size_t ws_size,
                              hipStream_t stream)
{
    const float* x  = (const float*)d_in[0];
    const float* Wk = (const float*)d_in[1];
    const float* Wq = (const float*)d_in[2];
    const float* Wv = (const float*)d_in[3];
    float* out = (float*)d_out;

    float* ws = (float*)d_ws;
    float* key64T = ws;                       // 4*64*64   = 16384 f32
    float* xpart  = key64T + 16384;           // 4*64*128  = 32768 f32
    float* vsum   = xpart + 32768;            // 4*128     = 512 f32
    unsigned short* Mth = (unsigned short*)(vsum + 512);   // 4*64*128 bf16
    unsigned short* Mtl = Mth + 32768;                     // 4*64*128 bf16
    unsigned short* Vt  = Mtl + 32768;                     // 4*128*64 bf16

    prep1<<<268, 256, 0, stream>>>(x, Wk, Wv, Vt, key64T, xpart);
    prep2<<<20, 256, 0, stream>>>(Wq, Wv, key64T, xpart, Mth, Mtl, vsum);
    attn_main<<<256, 256, 0, stream>>>(
        x, (const short*)Mth, (const short*)Mtl, (const short*)Vt, vsum, out);
}